// Round 6
// baseline (782.974 us; speedup 1.0000x reference)
//
#include <hip/hip_runtime.h>
#include <stdint.h>

#define PSEL 8192
#define PB 32

static __device__ __forceinline__ uint32_t fkey(float f) {
    uint32_t u = __float_as_uint(f);
    return (u & 0x80000000u) ? ~u : (u | 0x80000000u);
}
static __device__ __forceinline__ uint64_t make_key(uint32_t k32, uint32_t idx) {
    return ((uint64_t)k32 << 18) | (uint64_t)(0x3FFFFu ^ idx);
}

// 2x bilinear upsample (jax.image.resize semantics) + uncertainty key + per-call state init
__global__ void pr_up(const float* __restrict__ in, float* __restrict__ out,
                      uint32_t* __restrict__ keys, int Hc, int Wc,
                      uint64_t* __restrict__ prefix, uint32_t* __restrict__ krem,
                      uint32_t* __restrict__ cnt) {
    const int H = Hc * 2, W = Wc * 2, HW = H * W;
    int gid = blockIdx.x * blockDim.x + threadIdx.x;
    if (gid < 4) { prefix[gid] = 0ull; krem[gid] = PSEL; cnt[gid] = 0u; }
    if (gid >= 4 * HW) return;
    int w = gid % W;
    int t = gid / W;
    int h = t % H;
    int n = t / H;
    int kx = w >> 1, ky = h >> 1;
    int xlo, xhi, ylo, yhi; float wxl, wxh, wyl, wyh;
    if (w & 1) { xlo = kx; xhi = kx + 1; wxl = 0.75f; wxh = 0.25f; if (xhi >= Wc) { xhi = xlo; wxl = 1.0f; wxh = 0.0f; } }
    else       { xlo = kx - 1; xhi = kx; wxl = 0.25f; wxh = 0.75f; if (xlo < 0)  { xlo = xhi; wxl = 0.0f; wxh = 1.0f; } }
    if (h & 1) { ylo = ky; yhi = ky + 1; wyl = 0.75f; wyh = 0.25f; if (yhi >= Hc) { yhi = ylo; wyl = 1.0f; wyh = 0.0f; } }
    else       { ylo = ky - 1; yhi = ky; wyl = 0.25f; wyh = 0.75f; if (ylo < 0)  { ylo = yhi; wyl = 0.0f; wyh = 1.0f; } }
    float s0 = 0.f, s1 = 0.f, s2 = 0.f;
    #pragma unroll
    for (int c = 0; c < 3; c++) {
        const float* p = in + ((n * 3 + c) * Hc) * Wc;
        float tlo = wyl * p[ylo * Wc + xlo] + wyh * p[yhi * Wc + xlo];
        float thi = wyl * p[ylo * Wc + xhi] + wyh * p[yhi * Wc + xhi];
        float v = wxl * tlo + wxh * thi;
        out[((n * 3 + c) * H + h) * W + w] = v;
        if (c == 0) s0 = v; else if (c == 1) s1 = v; else s2 = v;
    }
    float m01 = fmaxf(s0, s1), mn01 = fminf(s0, s1);
    float mx = fmaxf(m01, s2);
    float sec = (s2 > m01) ? m01 : fmaxf(mn01, s2);
    keys[n * HW + h * W + w] = fkey(sec - mx);
}

// one radix-select pass: 10-bit digit histogram of keys matching current prefix
__global__ void pr_hist(const uint32_t* __restrict__ keys, const uint64_t* __restrict__ prefix,
                        uint32_t* __restrict__ hist, int HW, int shift) {
    __shared__ uint32_t lh[1024];
    const int n = blockIdx.y;
    for (int i = threadIdx.x; i < 1024; i += blockDim.x) lh[i] = 0u;
    __syncthreads();
    uint64_t pref = prefix[n];
    const uint32_t* kp = keys + (size_t)n * HW;
    int stride = gridDim.x * blockDim.x;
    for (int i = blockIdx.x * blockDim.x + threadIdx.x; i < HW; i += stride) {
        uint64_t key = make_key(kp[i], (uint32_t)i);
        if ((key >> (shift + 10)) == pref)
            atomicAdd(&lh[(uint32_t)(key >> shift) & 1023u], 1u);
    }
    __syncthreads();
    for (int i = threadIdx.x; i < 1024; i += blockDim.x) {
        uint32_t v = lh[i];
        if (v) atomicAdd(&hist[n * 1024 + i], v);
    }
}

// pick the digit containing the k-th largest; update state; zero hist for next pass
__global__ __launch_bounds__(256) void pr_scan(uint32_t* __restrict__ hist, uint64_t* __restrict__ prefix,
                                               uint32_t* __restrict__ krem, uint64_t* __restrict__ thr,
                                               int last) {
    const int n = blockIdx.x;
    const int t = threadIdx.x;
    __shared__ uint32_t h[1024];
    __shared__ uint32_t csum[256];
    __shared__ int sel_d;
    __shared__ uint32_t sel_above;
    uint32_t* hp = hist + n * 1024;
    uint32_t h0 = hp[t * 4 + 0], h1 = hp[t * 4 + 1], h2 = hp[t * 4 + 2], h3 = hp[t * 4 + 3];
    h[t * 4 + 0] = h0; h[t * 4 + 1] = h1; h[t * 4 + 2] = h2; h[t * 4 + 3] = h3;
    uint32_t s = h0 + h1 + h2 + h3;
    csum[t] = s;
    __syncthreads();
    for (int off = 1; off < 256; off <<= 1) {
        uint32_t add = (t + off < 256) ? csum[t + off] : 0u;
        __syncthreads();
        csum[t] += add;
        __syncthreads();
    }
    uint32_t krm = krem[n];
    uint32_t run = csum[t] - s;  // count in chunks strictly above t
    for (int b = 3; b >= 0; b--) {
        uint32_t hv = h[t * 4 + b];
        if (run < krm && krm <= run + hv) { sel_d = t * 4 + b; sel_above = run; }
        run += hv;
    }
    __syncthreads();
    if (t == 0) {
        uint64_t np = (prefix[n] << 10) | (uint64_t)(uint32_t)sel_d;
        prefix[n] = np;
        krem[n] = krm - sel_above;
        if (last) thr[n] = np;
    }
    hp[t * 4 + 0] = 0u; hp[t * 4 + 1] = 0u; hp[t * 4 + 2] = 0u; hp[t * 4 + 3] = 0u;
}

// gather all indices with key >= threshold (exactly PSEL per image, keys unique).
// Block-aggregated: LDS list + ONE global atomicAdd per block (order of pts is irrelevant).
__global__ __launch_bounds__(256) void pr_compact(const uint32_t* __restrict__ keys,
                                                  const uint64_t* __restrict__ thr,
                                                  uint32_t* __restrict__ cnt,
                                                  uint32_t* __restrict__ pts, int HW) {
    __shared__ uint32_t lbuf[4096];
    __shared__ uint32_t lcnt, gbase;
    const int n = blockIdx.y;
    const int t = threadIdx.x;
    if (t == 0) lcnt = 0u;
    __syncthreads();
    uint64_t T = thr[n];
    const uint32_t* kp = keys + (size_t)n * HW;
    int stride = gridDim.x * blockDim.x;
    for (int i = blockIdx.x * blockDim.x + t; i < HW; i += stride) {
        uint64_t key = make_key(kp[i], (uint32_t)i);
        if (key >= T) {
            uint32_t p = atomicAdd(&lcnt, 1u);
            if (p < 4096u) lbuf[p] = (uint32_t)i;
        }
    }
    __syncthreads();
    if (t == 0) gbase = atomicAdd(&cnt[n], lcnt);
    __syncthreads();
    uint32_t m = lcnt;
    uint32_t gb = gbase;
    for (uint32_t j = t; j < m; j += 256u) {
        uint32_t pos = gb + j;
        if (pos < PSEL) pts[n * PSEL + pos] = lbuf[j];
    }
}

// per-image ascending bitonic sort of the 8192 selected indices (spatial clustering
// for the mlp gather: consecutive lanes -> adjacent pixels -> shared cachelines).
// Output values are unaffected (per-point math independent of order).
__global__ __launch_bounds__(1024) void pr_sort(uint32_t* __restrict__ pts) {
    __shared__ uint32_t s[PSEL];
    const int n = blockIdx.x;
    uint32_t* p = pts + n * PSEL;
    for (int i = threadIdx.x; i < PSEL; i += 1024) s[i] = p[i];
    __syncthreads();
    for (int k = 2; k <= PSEL; k <<= 1) {
        for (int j = k >> 1; j > 0; j >>= 1) {
            for (int i = threadIdx.x; i < PSEL; i += 1024) {
                int ixj = i ^ j;
                if (ixj > i) {
                    uint32_t a = s[i], b = s[ixj];
                    bool up = ((i & k) == 0);
                    if (up ? (a > b) : (a < b)) { s[i] = b; s[ixj] = a; }
                }
            }
            __syncthreads();
        }
    }
    for (int i = threadIdx.x; i < PSEL; i += 1024) p[i] = s[i];
}

// point head v2: 32 pts/block, 256 threads. thread=(o2 = t&63 -> channels o2,o2+64; ph = t>>6 -> 8 pts)
// fp32 throughout, op order identical to v1 (selection stability for step 2).
__global__ __launch_bounds__(256) void pr_mlp2(
        const float* __restrict__ feat, const float* __restrict__ coarse,
        const float* __restrict__ w1, const float* __restrict__ b1,
        const float* __restrict__ w2, const float* __restrict__ b2,
        const float* __restrict__ w3, const float* __restrict__ b3,
        const float* __restrict__ wp, const float* __restrict__ bp,
        const uint32_t* __restrict__ pts, float* __restrict__ sem, int W) {
    __shared__ __align__(16) float xbuf[131 * 36];
    __shared__ float wchunk[128 * 33];
    __shared__ uint32_t ptl[PB];
    const int t = threadIdx.x;
    const int n = blockIdx.y;
    if (t < PB) ptl[t] = pts[n * PSEL + blockIdx.x * PB + t];
    __syncthreads();
    const int lw = (W == 512) ? 9 : 8;
    // ---- gather fine: thread = (pt = t&31, csl = t>>5 -> 16 channels) ----
    {
        const int pt = t & 31, csl = t >> 5;
        uint32_t idx = ptl[pt];
        int ix = (int)(idx & (uint32_t)(W - 1));
        int iy = (int)(idx >> lw);
        const float* fb = feat + (size_t)n * 128 * 65536;
        if (W == 256) {
            // sample coords are exactly integer pixels: direct load
            const float* p0 = fb + (size_t)(csl * 16) * 65536 + iy * 256 + ix;
            #pragma unroll 4
            for (int k = 0; k < 16; k++)
                xbuf[(csl * 16 + k) * 36 + pt] = p0[(size_t)k * 65536];
        } else {
            float px = ((float)ix + 0.5f) / (float)W;
            float py = ((float)iy + 0.5f) / (float)W;
            float fx = px * 256.0f - 0.5f, fy = py * 256.0f - 0.5f;
            float x0f = floorf(fx), y0f = floorf(fy);
            int x0 = (int)x0f, y0 = (int)y0f;
            float wx1 = fx - x0f, wy1 = fy - y0f;
            float wx0 = 1.0f - wx1, wy0 = 1.0f - wy1;
            int x1 = x0 + 1, y1 = y0 + 1;
            float vx0 = (x0 >= 0 && x0 < 256) ? 1.0f : 0.0f;
            float vx1 = (x1 >= 0 && x1 < 256) ? 1.0f : 0.0f;
            float vy0 = (y0 >= 0 && y0 < 256) ? 1.0f : 0.0f;
            float vy1 = (y1 >= 0 && y1 < 256) ? 1.0f : 0.0f;
            int xc0 = min(max(x0, 0), 255), xc1 = min(max(x1, 0), 255);
            int yc0 = min(max(y0, 0), 255), yc1 = min(max(y1, 0), 255);
            int o00 = yc0 * 256 + xc0, o01 = yc0 * 256 + xc1;
            int o10 = yc1 * 256 + xc0, o11 = yc1 * 256 + xc1;
            float w00 = (wx0 * wy0) * (vx0 * vy0), w01 = (wx1 * wy0) * (vx1 * vy0);
            float w10 = (wx0 * wy1) * (vx0 * vy1), w11 = (wx1 * wy1) * (vx1 * vy1);
            const float* p0 = fb + (size_t)(csl * 16) * 65536;
            #pragma unroll 2
            for (int k = 0; k < 16; k++) {
                const float* p = p0 + (size_t)k * 65536;
                float v = p[o00] * w00 + p[o01] * w01 + p[o10] * w10 + p[o11] * w11;
                xbuf[(csl * 16 + k) * 36 + pt] = v;
            }
        }
    }
    // ---- gather coarse (3 channels, always bilinear on 128x128) ----
    if (t < 96) {
        const int pt = t & 31, cc = t >> 5;
        uint32_t idx = ptl[pt];
        int ix = (int)(idx & (uint32_t)(W - 1));
        int iy = (int)(idx >> lw);
        float px = ((float)ix + 0.5f) / (float)W;
        float py = ((float)iy + 0.5f) / (float)W;
        float gx = px * 128.0f - 0.5f, gy = py * 128.0f - 0.5f;
        float x0f = floorf(gx), y0f = floorf(gy);
        int x0 = (int)x0f, y0 = (int)y0f;
        float u1 = gx - x0f, v1 = gy - y0f;
        float u0 = 1.0f - u1, v0 = 1.0f - v1;
        int x1 = x0 + 1, y1 = y0 + 1;
        float vx0 = (x0 >= 0 && x0 < 128) ? 1.0f : 0.0f;
        float vx1 = (x1 >= 0 && x1 < 128) ? 1.0f : 0.0f;
        float vy0 = (y0 >= 0 && y0 < 128) ? 1.0f : 0.0f;
        float vy1 = (y1 >= 0 && y1 < 128) ? 1.0f : 0.0f;
        int xc0 = min(max(x0, 0), 127), xc1 = min(max(x1, 0), 127);
        int yc0 = min(max(y0, 0), 127), yc1 = min(max(y1, 0), 127);
        const float* cb = coarse + ((size_t)(n * 3 + cc)) * 16384;
        float v = cb[yc0 * 128 + xc0] * ((u0 * v0) * (vx0 * vy0))
                + cb[yc0 * 128 + xc1] * ((u1 * v0) * (vx1 * vy0))
                + cb[yc1 * 128 + xc0] * ((u0 * v1) * (vx0 * vy1))
                + cb[yc1 * 128 + xc1] * ((u1 * v1) * (vx1 * vy1));
        xbuf[(128 + cc) * 36 + pt] = v;
    }
    __syncthreads();
    // ---- 3 hidden layers ----
    const int o2 = t & 63, ph = t >> 6;
    float accA[8], accB[8];

    auto layer = [&](const float* __restrict__ Wg, const float* __restrict__ Bg) {
        float bA = Bg[o2], bB = Bg[o2 + 64];
        #pragma unroll
        for (int j = 0; j < 8; j++) { accA[j] = bA; accB[j] = bB; }
        for (int i0 = 0; i0 < 128; i0 += 32) {
            __syncthreads();
            for (int j = t; j < 4096; j += 256) {
                int o = j >> 5, ii = j & 31;
                wchunk[o * 33 + ii] = Wg[o * 131 + i0 + ii];
            }
            __syncthreads();
            #pragma unroll
            for (int ii = 0; ii < 32; ii++) {
                float wA = wchunk[o2 * 33 + ii];
                float wB = wchunk[(o2 + 64) * 33 + ii];
                const float4* xr = (const float4*)&xbuf[(i0 + ii) * 36 + ph * 8];
                float4 xv0 = xr[0], xv1 = xr[1];
                accA[0] = fmaf(wA, xv0.x, accA[0]); accA[1] = fmaf(wA, xv0.y, accA[1]);
                accA[2] = fmaf(wA, xv0.z, accA[2]); accA[3] = fmaf(wA, xv0.w, accA[3]);
                accA[4] = fmaf(wA, xv1.x, accA[4]); accA[5] = fmaf(wA, xv1.y, accA[5]);
                accA[6] = fmaf(wA, xv1.z, accA[6]); accA[7] = fmaf(wA, xv1.w, accA[7]);
                accB[0] = fmaf(wB, xv0.x, accB[0]); accB[1] = fmaf(wB, xv0.y, accB[1]);
                accB[2] = fmaf(wB, xv0.z, accB[2]); accB[3] = fmaf(wB, xv0.w, accB[3]);
                accB[4] = fmaf(wB, xv1.x, accB[4]); accB[5] = fmaf(wB, xv1.y, accB[5]);
                accB[6] = fmaf(wB, xv1.z, accB[6]); accB[7] = fmaf(wB, xv1.w, accB[7]);
            }
        }
        // tail i = 128..130 (coarse rows)
        __syncthreads();
        for (int j = t; j < 384; j += 256) {
            int o = j / 3, ii = j - o * 3;
            wchunk[o * 33 + ii] = Wg[o * 131 + 128 + ii];
        }
        __syncthreads();
        #pragma unroll
        for (int ii = 0; ii < 3; ii++) {
            float wA = wchunk[o2 * 33 + ii];
            float wB = wchunk[(o2 + 64) * 33 + ii];
            const float4* xr = (const float4*)&xbuf[(128 + ii) * 36 + ph * 8];
            float4 xv0 = xr[0], xv1 = xr[1];
            accA[0] = fmaf(wA, xv0.x, accA[0]); accA[1] = fmaf(wA, xv0.y, accA[1]);
            accA[2] = fmaf(wA, xv0.z, accA[2]); accA[3] = fmaf(wA, xv0.w, accA[3]);
            accA[4] = fmaf(wA, xv1.x, accA[4]); accA[5] = fmaf(wA, xv1.y, accA[5]);
            accA[6] = fmaf(wA, xv1.z, accA[6]); accA[7] = fmaf(wA, xv1.w, accA[7]);
            accB[0] = fmaf(wB, xv0.x, accB[0]); accB[1] = fmaf(wB, xv0.y, accB[1]);
            accB[2] = fmaf(wB, xv0.z, accB[2]); accB[3] = fmaf(wB, xv0.w, accB[3]);
            accB[4] = fmaf(wB, xv1.x, accB[4]); accB[5] = fmaf(wB, xv1.y, accB[5]);
            accB[6] = fmaf(wB, xv1.z, accB[6]); accB[7] = fmaf(wB, xv1.w, accB[7]);
        }
        __syncthreads();  // all reads of xbuf done before overwrite
        #pragma unroll
        for (int j = 0; j < 8; j++) {
            xbuf[o2 * 36 + ph * 8 + j] = fmaxf(accA[j], 0.0f);
            xbuf[(o2 + 64) * 36 + ph * 8 + j] = fmaxf(accB[j], 0.0f);
        }
    };
    layer(w1, b1);
    layer(w2, b2);
    layer(w3, b3);
    __syncthreads();
    // ---- head 3x131 + scatter ----
    if (t < 96) {
        int cc = t >> 5, pt = t & 31;
        float acc = bp[cc];
        const float* wr = wp + cc * 131;
        for (int i = 0; i < 131; i++)
            acc = fmaf(wr[i], xbuf[i * 36 + pt], acc);
        sem[((size_t)(n * 3 + cc)) * W * W + ptl[pt]] = acc;
    }
}

extern "C" void kernel_launch(void* const* d_in, const int* in_sizes, int n_in,
                              void* d_out, int out_size, void* d_ws, size_t ws_size,
                              hipStream_t stream) {
    const float* coarse = (const float*)d_in[0];
    const float* feat   = (const float*)d_in[1];
    const float* w1 = (const float*)d_in[2];
    const float* b1 = (const float*)d_in[3];
    const float* w2 = (const float*)d_in[4];
    const float* b2 = (const float*)d_in[5];
    const float* w3 = (const float*)d_in[6];
    const float* b3 = (const float*)d_in[7];
    const float* wp = (const float*)d_in[8];
    const float* bp = (const float*)d_in[9];
    float* out = (float*)d_out;

    char* base = (char*)d_ws;
    float*    sem1   = (float*)base;                      // 4*3*256*256*4 = 3,145,728
    uint32_t* keys   = (uint32_t*)(base + 3145728);       // 4*262144*4    = 4,194,304
    uint32_t* hist   = (uint32_t*)(base + 7340032);       // 4*1024*4      = 16,384
    uint64_t* prefix = (uint64_t*)(base + 7356416);       // 32
    uint64_t* thr    = (uint64_t*)(base + 7356448);       // 32
    uint32_t* krem   = (uint32_t*)(base + 7356480);       // 16
    uint32_t* cnt    = (uint32_t*)(base + 7356496);       // 16
    uint32_t* pts    = (uint32_t*)(base + 7356512);       // 4*8192*4 = 131,072
    if (ws_size < (size_t)7487584) return;

    hipMemsetAsync(hist, 0, 4 * 1024 * sizeof(uint32_t), stream);

    for (int step = 0; step < 2; step++) {
        const float* sin_ = (step == 0) ? coarse : sem1;
        float* sout = (step == 0) ? sem1 : out;
        int Hc = (step == 0) ? 128 : 256;
        int H = 2 * Hc, HW = H * H;
        int total = 4 * HW;
        pr_up<<<dim3((total + 255) / 256), dim3(256), 0, stream>>>(
            sin_, sout, keys, Hc, Hc, prefix, krem, cnt);
        for (int p = 0; p < 5; p++) {
            int shift = 40 - 10 * p;
            pr_hist<<<dim3(16, 4), dim3(256), 0, stream>>>(keys, prefix, hist, HW, shift);
            pr_scan<<<dim3(4), dim3(256), 0, stream>>>(hist, prefix, krem, thr, p == 4 ? 1 : 0);
        }
        pr_compact<<<dim3(64, 4), dim3(256), 0, stream>>>(keys, thr, cnt, pts, HW);
        pr_sort<<<dim3(4), dim3(1024), 0, stream>>>(pts);
        pr_mlp2<<<dim3(PSEL / PB, 4), dim3(256), 0, stream>>>(
            feat, coarse, w1, b1, w2, b2, w3, b3, wp, bp, pts, sout, H);
    }
}

// Round 8
// 537.286 us; speedup vs baseline: 1.4573x; 1.4573x over previous
//
#include <hip/hip_runtime.h>
#include <stdint.h>

#define PSEL 8192
#define PB 32

static __device__ __forceinline__ uint32_t fkey(float f) {
    uint32_t u = __float_as_uint(f);
    return (u & 0x80000000u) ? ~u : (u | 0x80000000u);
}
static __device__ __forceinline__ uint64_t make_key(uint32_t k32, uint32_t idx) {
    return ((uint64_t)k32 << 18) | (uint64_t)(0x3FFFFu ^ idx);
}

// 2x bilinear upsample (jax.image.resize semantics) + uncertainty key + per-call state init
__global__ void pr_up(const float* __restrict__ in, float* __restrict__ out,
                      uint32_t* __restrict__ keys, int Hc, int Wc,
                      uint64_t* __restrict__ prefix, uint32_t* __restrict__ krem) {
    const int H = Hc * 2, W = Wc * 2, HW = H * W;
    int gid = blockIdx.x * blockDim.x + threadIdx.x;
    if (gid < 4) { prefix[gid] = 0ull; krem[gid] = PSEL; }
    if (gid >= 4 * HW) return;
    int w = gid % W;
    int t = gid / W;
    int h = t % H;
    int n = t / H;
    int kx = w >> 1, ky = h >> 1;
    int xlo, xhi, ylo, yhi; float wxl, wxh, wyl, wyh;
    if (w & 1) { xlo = kx; xhi = kx + 1; wxl = 0.75f; wxh = 0.25f; if (xhi >= Wc) { xhi = xlo; wxl = 1.0f; wxh = 0.0f; } }
    else       { xlo = kx - 1; xhi = kx; wxl = 0.25f; wxh = 0.75f; if (xlo < 0)  { xlo = xhi; wxl = 0.0f; wxh = 1.0f; } }
    if (h & 1) { ylo = ky; yhi = ky + 1; wyl = 0.75f; wyh = 0.25f; if (yhi >= Hc) { yhi = ylo; wyl = 1.0f; wyh = 0.0f; } }
    else       { ylo = ky - 1; yhi = ky; wyl = 0.25f; wyh = 0.75f; if (ylo < 0)  { ylo = yhi; wyl = 0.0f; wyh = 1.0f; } }
    float s0 = 0.f, s1 = 0.f, s2 = 0.f;
    #pragma unroll
    for (int c = 0; c < 3; c++) {
        const float* p = in + ((n * 3 + c) * Hc) * Wc;
        float tlo = wyl * p[ylo * Wc + xlo] + wyh * p[yhi * Wc + xlo];
        float thi = wyl * p[ylo * Wc + xhi] + wyh * p[yhi * Wc + xhi];
        float v = wxl * tlo + wxh * thi;
        out[((n * 3 + c) * H + h) * W + w] = v;
        if (c == 0) s0 = v; else if (c == 1) s1 = v; else s2 = v;
    }
    float m01 = fmaxf(s0, s1), mn01 = fminf(s0, s1);
    float mx = fmaxf(m01, s2);
    float sec = (s2 > m01) ? m01 : fmaxf(mn01, s2);
    keys[n * HW + h * W + w] = fkey(sec - mx);
}

// one radix-select pass: 10-bit digit histogram of keys matching current prefix
__global__ void pr_hist(const uint32_t* __restrict__ keys, const uint64_t* __restrict__ prefix,
                        uint32_t* __restrict__ hist, int HW, int shift) {
    __shared__ uint32_t lh[1024];
    const int n = blockIdx.y;
    for (int i = threadIdx.x; i < 1024; i += blockDim.x) lh[i] = 0u;
    __syncthreads();
    uint64_t pref = prefix[n];
    const uint32_t* kp = keys + (size_t)n * HW;
    int stride = gridDim.x * blockDim.x;
    for (int i = blockIdx.x * blockDim.x + threadIdx.x; i < HW; i += stride) {
        uint64_t key = make_key(kp[i], (uint32_t)i);
        if ((key >> (shift + 10)) == pref)
            atomicAdd(&lh[(uint32_t)(key >> shift) & 1023u], 1u);
    }
    __syncthreads();
    for (int i = threadIdx.x; i < 1024; i += blockDim.x) {
        uint32_t v = lh[i];
        if (v) atomicAdd(&hist[n * 1024 + i], v);
    }
}

// pick the digit containing the k-th largest; update state; zero hist for next pass
__global__ __launch_bounds__(256) void pr_scan(uint32_t* __restrict__ hist, uint64_t* __restrict__ prefix,
                                               uint32_t* __restrict__ krem, uint64_t* __restrict__ thr,
                                               int last) {
    const int n = blockIdx.x;
    const int t = threadIdx.x;
    __shared__ uint32_t h[1024];
    __shared__ uint32_t csum[256];
    __shared__ int sel_d;
    __shared__ uint32_t sel_above;
    uint32_t* hp = hist + n * 1024;
    uint32_t h0 = hp[t * 4 + 0], h1 = hp[t * 4 + 1], h2 = hp[t * 4 + 2], h3 = hp[t * 4 + 3];
    h[t * 4 + 0] = h0; h[t * 4 + 1] = h1; h[t * 4 + 2] = h2; h[t * 4 + 3] = h3;
    uint32_t s = h0 + h1 + h2 + h3;
    csum[t] = s;
    __syncthreads();
    for (int off = 1; off < 256; off <<= 1) {
        uint32_t add = (t + off < 256) ? csum[t + off] : 0u;
        __syncthreads();
        csum[t] += add;
        __syncthreads();
    }
    uint32_t krm = krem[n];
    uint32_t run = csum[t] - s;  // count in chunks strictly above t
    for (int b = 3; b >= 0; b--) {
        uint32_t hv = h[t * 4 + b];
        if (run < krm && krm <= run + hv) { sel_d = t * 4 + b; sel_above = run; }
        run += hv;
    }
    __syncthreads();
    if (t == 0) {
        uint64_t np = (prefix[n] << 10) | (uint64_t)(uint32_t)sel_d;
        prefix[n] = np;
        krem[n] = krm - sel_above;
        if (last) thr[n] = np;
    }
    hp[t * 4 + 0] = 0u; hp[t * 4 + 1] = 0u; hp[t * 4 + 2] = 0u; hp[t * 4 + 3] = 0u;
}

// ---- order-preserving compaction: count -> scan -> emit (pts comes out ascending) ----
// Each block covers a contiguous pixel range; each thread a contiguous sub-range of HW/16384 px.
__global__ __launch_bounds__(256) void pr_count(const uint32_t* __restrict__ keys,
                                                const uint64_t* __restrict__ thr,
                                                uint32_t* __restrict__ bcnt, int HW) {
    __shared__ uint32_t red[256];
    const int n = blockIdx.y, b = blockIdx.x, t = threadIdx.x;
    const int per = HW >> 14;  // 64 blocks * 256 threads * per = HW
    const uint64_t T = thr[n];
    const uint32_t* kp = keys + (size_t)n * HW;
    int start = (b * 256 + t) * per;
    uint32_t c = 0;
    for (int k = 0; k < per; k++) {
        int i = start + k;
        c += (make_key(kp[i], (uint32_t)i) >= T) ? 1u : 0u;
    }
    red[t] = c;
    __syncthreads();
    for (int off = 128; off > 0; off >>= 1) {
        if (t < off) red[t] += red[t + off];
        __syncthreads();
    }
    if (t == 0) bcnt[n * 64 + b] = red[0];
}

// segmented exclusive scan of the 4x64 block counts (one tiny block)
__global__ __launch_bounds__(256) void pr_bscan(const uint32_t* __restrict__ bcnt,
                                                uint32_t* __restrict__ bbase) {
    __shared__ uint32_t s[256];
    const int t = threadIdx.x;
    uint32_t v = bcnt[t];
    s[t] = v;
    __syncthreads();
    for (int off = 1; off < 64; off <<= 1) {
        uint32_t add = ((t & 63) >= off) ? s[t - off] : 0u;
        __syncthreads();
        s[t] += add;
        __syncthreads();
    }
    bbase[t] = s[t] - v;  // exclusive within each 64-segment (image)
}

__global__ __launch_bounds__(256) void pr_emit(const uint32_t* __restrict__ keys,
                                               const uint64_t* __restrict__ thr,
                                               const uint32_t* __restrict__ bbase,
                                               uint32_t* __restrict__ pts, int HW) {
    __shared__ uint32_t s[256];
    const int n = blockIdx.y, b = blockIdx.x, t = threadIdx.x;
    const int per = HW >> 14;
    const uint64_t T = thr[n];
    const uint32_t* kp = keys + (size_t)n * HW;
    int start = (b * 256 + t) * per;
    uint32_t c = 0;
    for (int k = 0; k < per; k++) {
        int i = start + k;
        c += (make_key(kp[i], (uint32_t)i) >= T) ? 1u : 0u;
    }
    s[t] = c;
    __syncthreads();
    for (int off = 1; off < 256; off <<= 1) {
        uint32_t add = (t >= off) ? s[t - off] : 0u;
        __syncthreads();
        s[t] += add;
        __syncthreads();
    }
    uint32_t pos = bbase[n * 64 + b] + s[t] - c;  // global ascending position
    uint32_t* pp = pts + n * PSEL;
    for (int k = 0; k < per; k++) {
        int i = start + k;
        if (make_key(kp[i], (uint32_t)i) >= T) {
            if (pos < PSEL) pp[pos] = (uint32_t)i;
            pos++;
        }
    }
}

// point head v2: 32 pts/block, 256 threads. thread=(o2 = t&63 -> channels o2,o2+64; ph = t>>6 -> 8 pts)
// fp32 throughout, op order identical to v1 (selection stability for step 2).
__global__ __launch_bounds__(256) void pr_mlp2(
        const float* __restrict__ feat, const float* __restrict__ coarse,
        const float* __restrict__ w1, const float* __restrict__ b1,
        const float* __restrict__ w2, const float* __restrict__ b2,
        const float* __restrict__ w3, const float* __restrict__ b3,
        const float* __restrict__ wp, const float* __restrict__ bp,
        const uint32_t* __restrict__ pts, float* __restrict__ sem, int W) {
    __shared__ __align__(16) float xbuf[131 * 36];
    __shared__ float wchunk[128 * 33];
    __shared__ uint32_t ptl[PB];
    const int t = threadIdx.x;
    const int n = blockIdx.y;
    if (t < PB) ptl[t] = pts[n * PSEL + blockIdx.x * PB + t];
    __syncthreads();
    const int lw = (W == 512) ? 9 : 8;
    // ---- gather fine: thread = (pt = t&31, csl = t>>5 -> 16 channels) ----
    {
        const int pt = t & 31, csl = t >> 5;
        uint32_t idx = ptl[pt];
        int ix = (int)(idx & (uint32_t)(W - 1));
        int iy = (int)(idx >> lw);
        const float* fb = feat + (size_t)n * 128 * 65536;
        if (W == 256) {
            // sample coords are exactly integer pixels: direct load
            const float* p0 = fb + (size_t)(csl * 16) * 65536 + iy * 256 + ix;
            #pragma unroll 4
            for (int k = 0; k < 16; k++)
                xbuf[(csl * 16 + k) * 36 + pt] = p0[(size_t)k * 65536];
        } else {
            float px = ((float)ix + 0.5f) / (float)W;
            float py = ((float)iy + 0.5f) / (float)W;
            float fx = px * 256.0f - 0.5f, fy = py * 256.0f - 0.5f;
            float x0f = floorf(fx), y0f = floorf(fy);
            int x0 = (int)x0f, y0 = (int)y0f;
            float wx1 = fx - x0f, wy1 = fy - y0f;
            float wx0 = 1.0f - wx1, wy0 = 1.0f - wy1;
            int x1 = x0 + 1, y1 = y0 + 1;
            float vx0 = (x0 >= 0 && x0 < 256) ? 1.0f : 0.0f;
            float vx1 = (x1 >= 0 && x1 < 256) ? 1.0f : 0.0f;
            float vy0 = (y0 >= 0 && y0 < 256) ? 1.0f : 0.0f;
            float vy1 = (y1 >= 0 && y1 < 256) ? 1.0f : 0.0f;
            int xc0 = min(max(x0, 0), 255), xc1 = min(max(x1, 0), 255);
            int yc0 = min(max(y0, 0), 255), yc1 = min(max(y1, 0), 255);
            int o00 = yc0 * 256 + xc0, o01 = yc0 * 256 + xc1;
            int o10 = yc1 * 256 + xc0, o11 = yc1 * 256 + xc1;
            float w00 = (wx0 * wy0) * (vx0 * vy0), w01 = (wx1 * wy0) * (vx1 * vy0);
            float w10 = (wx0 * wy1) * (vx0 * vy1), w11 = (wx1 * wy1) * (vx1 * vy1);
            const float* p0 = fb + (size_t)(csl * 16) * 65536;
            #pragma unroll 2
            for (int k = 0; k < 16; k++) {
                const float* p = p0 + (size_t)k * 65536;
                float v = p[o00] * w00 + p[o01] * w01 + p[o10] * w10 + p[o11] * w11;
                xbuf[(csl * 16 + k) * 36 + pt] = v;
            }
        }
    }
    // ---- gather coarse (3 channels, always bilinear on 128x128) ----
    if (t < 96) {
        const int pt = t & 31, cc = t >> 5;
        uint32_t idx = ptl[pt];
        int ix = (int)(idx & (uint32_t)(W - 1));
        int iy = (int)(idx >> lw);
        float px = ((float)ix + 0.5f) / (float)W;
        float py = ((float)iy + 0.5f) / (float)W;
        float gx = px * 128.0f - 0.5f, gy = py * 128.0f - 0.5f;
        float x0f = floorf(gx), y0f = floorf(gy);
        int x0 = (int)x0f, y0 = (int)y0f;
        float u1 = gx - x0f, v1 = gy - y0f;
        float u0 = 1.0f - u1, v0 = 1.0f - v1;
        int x1 = x0 + 1, y1 = y0 + 1;
        float vx0 = (x0 >= 0 && x0 < 128) ? 1.0f : 0.0f;
        float vx1 = (x1 >= 0 && x1 < 128) ? 1.0f : 0.0f;
        float vy0 = (y0 >= 0 && y0 < 128) ? 1.0f : 0.0f;
        float vy1 = (y1 >= 0 && y1 < 128) ? 1.0f : 0.0f;
        int xc0 = min(max(x0, 0), 127), xc1 = min(max(x1, 0), 127);
        int yc0 = min(max(y0, 0), 127), yc1 = min(max(y1, 0), 127);
        const float* cb = coarse + ((size_t)(n * 3 + cc)) * 16384;
        float v = cb[yc0 * 128 + xc0] * ((u0 * v0) * (vx0 * vy0))
                + cb[yc0 * 128 + xc1] * ((u1 * v0) * (vx1 * vy0))
                + cb[yc1 * 128 + xc0] * ((u0 * v1) * (vx0 * vy1))
                + cb[yc1 * 128 + xc1] * ((u1 * v1) * (vx1 * vy1));
        xbuf[(128 + cc) * 36 + pt] = v;
    }
    __syncthreads();
    // ---- 3 hidden layers ----
    const int o2 = t & 63, ph = t >> 6;
    float accA[8], accB[8];

    auto layer = [&](const float* __restrict__ Wg, const float* __restrict__ Bg) {
        float bA = Bg[o2], bB = Bg[o2 + 64];
        #pragma unroll
        for (int j = 0; j < 8; j++) { accA[j] = bA; accB[j] = bB; }
        for (int i0 = 0; i0 < 128; i0 += 32) {
            __syncthreads();
            for (int j = t; j < 4096; j += 256) {
                int o = j >> 5, ii = j & 31;
                wchunk[o * 33 + ii] = Wg[o * 131 + i0 + ii];
            }
            __syncthreads();
            #pragma unroll
            for (int ii = 0; ii < 32; ii++) {
                float wA = wchunk[o2 * 33 + ii];
                float wB = wchunk[(o2 + 64) * 33 + ii];
                const float4* xr = (const float4*)&xbuf[(i0 + ii) * 36 + ph * 8];
                float4 xv0 = xr[0], xv1 = xr[1];
                accA[0] = fmaf(wA, xv0.x, accA[0]); accA[1] = fmaf(wA, xv0.y, accA[1]);
                accA[2] = fmaf(wA, xv0.z, accA[2]); accA[3] = fmaf(wA, xv0.w, accA[3]);
                accA[4] = fmaf(wA, xv1.x, accA[4]); accA[5] = fmaf(wA, xv1.y, accA[5]);
                accA[6] = fmaf(wA, xv1.z, accA[6]); accA[7] = fmaf(wA, xv1.w, accA[7]);
                accB[0] = fmaf(wB, xv0.x, accB[0]); accB[1] = fmaf(wB, xv0.y, accB[1]);
                accB[2] = fmaf(wB, xv0.z, accB[2]); accB[3] = fmaf(wB, xv0.w, accB[3]);
                accB[4] = fmaf(wB, xv1.x, accB[4]); accB[5] = fmaf(wB, xv1.y, accB[5]);
                accB[6] = fmaf(wB, xv1.z, accB[6]); accB[7] = fmaf(wB, xv1.w, accB[7]);
            }
        }
        // tail i = 128..130 (coarse rows)
        __syncthreads();
        for (int j = t; j < 384; j += 256) {
            int o = j / 3, ii = j - o * 3;
            wchunk[o * 33 + ii] = Wg[o * 131 + 128 + ii];
        }
        __syncthreads();
        #pragma unroll
        for (int ii = 0; ii < 3; ii++) {
            float wA = wchunk[o2 * 33 + ii];
            float wB = wchunk[(o2 + 64) * 33 + ii];
            const float4* xr = (const float4*)&xbuf[(128 + ii) * 36 + ph * 8];
            float4 xv0 = xr[0], xv1 = xr[1];
            accA[0] = fmaf(wA, xv0.x, accA[0]); accA[1] = fmaf(wA, xv0.y, accA[1]);
            accA[2] = fmaf(wA, xv0.z, accA[2]); accA[3] = fmaf(wA, xv0.w, accA[3]);
            accA[4] = fmaf(wA, xv1.x, accA[4]); accA[5] = fmaf(wA, xv1.y, accA[5]);
            accA[6] = fmaf(wA, xv1.z, accA[6]); accA[7] = fmaf(wA, xv1.w, accA[7]);
            accB[0] = fmaf(wB, xv0.x, accB[0]); accB[1] = fmaf(wB, xv0.y, accB[1]);
            accB[2] = fmaf(wB, xv0.z, accB[2]); accB[3] = fmaf(wB, xv0.w, accB[3]);
            accB[4] = fmaf(wB, xv1.x, accB[4]); accB[5] = fmaf(wB, xv1.y, accB[5]);
            accB[6] = fmaf(wB, xv1.z, accB[6]); accB[7] = fmaf(wB, xv1.w, accB[7]);
        }
        __syncthreads();  // all reads of xbuf done before overwrite
        #pragma unroll
        for (int j = 0; j < 8; j++) {
            xbuf[o2 * 36 + ph * 8 + j] = fmaxf(accA[j], 0.0f);
            xbuf[(o2 + 64) * 36 + ph * 8 + j] = fmaxf(accB[j], 0.0f);
        }
    };
    layer(w1, b1);
    layer(w2, b2);
    layer(w3, b3);
    __syncthreads();
    // ---- head 3x131 + scatter ----
    if (t < 96) {
        int cc = t >> 5, pt = t & 31;
        float acc = bp[cc];
        const float* wr = wp + cc * 131;
        for (int i = 0; i < 131; i++)
            acc = fmaf(wr[i], xbuf[i * 36 + pt], acc);
        sem[((size_t)(n * 3 + cc)) * W * W + ptl[pt]] = acc;
    }
}

extern "C" void kernel_launch(void* const* d_in, const int* in_sizes, int n_in,
                              void* d_out, int out_size, void* d_ws, size_t ws_size,
                              hipStream_t stream) {
    const float* coarse = (const float*)d_in[0];
    const float* feat   = (const float*)d_in[1];
    const float* w1 = (const float*)d_in[2];
    const float* b1 = (const float*)d_in[3];
    const float* w2 = (const float*)d_in[4];
    const float* b2 = (const float*)d_in[5];
    const float* w3 = (const float*)d_in[6];
    const float* b3 = (const float*)d_in[7];
    const float* wp = (const float*)d_in[8];
    const float* bp = (const float*)d_in[9];
    float* out = (float*)d_out;

    char* base = (char*)d_ws;
    float*    sem1   = (float*)base;                      // 4*3*256*256*4 = 3,145,728
    uint32_t* keys   = (uint32_t*)(base + 3145728);       // 4*262144*4    = 4,194,304
    uint32_t* hist   = (uint32_t*)(base + 7340032);       // 4*1024*4      = 16,384
    uint64_t* prefix = (uint64_t*)(base + 7356416);       // 32
    uint64_t* thr    = (uint64_t*)(base + 7356448);       // 32
    uint32_t* krem   = (uint32_t*)(base + 7356480);       // 16 (+pad 16)
    uint32_t* pts    = (uint32_t*)(base + 7356512);       // 4*8192*4 = 131,072
    uint32_t* bcnt   = (uint32_t*)(base + 7487584);       // 256*4 = 1,024
    uint32_t* bbase  = (uint32_t*)(base + 7488608);       // 256*4 = 1,024
    if (ws_size < (size_t)7489632) return;

    hipMemsetAsync(hist, 0, 4 * 1024 * sizeof(uint32_t), stream);

    for (int step = 0; step < 2; step++) {
        const float* sin_ = (step == 0) ? coarse : sem1;
        float* sout = (step == 0) ? sem1 : out;
        int Hc = (step == 0) ? 128 : 256;
        int H = 2 * Hc, HW = H * H;
        int total = 4 * HW;
        pr_up<<<dim3((total + 255) / 256), dim3(256), 0, stream>>>(
            sin_, sout, keys, Hc, Hc, prefix, krem);
        for (int p = 0; p < 5; p++) {
            int shift = 40 - 10 * p;
            pr_hist<<<dim3(16, 4), dim3(256), 0, stream>>>(keys, prefix, hist, HW, shift);
            pr_scan<<<dim3(4), dim3(256), 0, stream>>>(hist, prefix, krem, thr, p == 4 ? 1 : 0);
        }
        pr_count<<<dim3(64, 4), dim3(256), 0, stream>>>(keys, thr, bcnt, HW);
        pr_bscan<<<dim3(1), dim3(256), 0, stream>>>(bcnt, bbase);
        pr_emit<<<dim3(64, 4), dim3(256), 0, stream>>>(keys, thr, bbase, pts, HW);
        pr_mlp2<<<dim3(PSEL / PB, 4), dim3(256), 0, stream>>>(
            feat, coarse, w1, b1, w2, b2, w3, b3, wp, bp, pts, sout, H);
    }
}